// Round 14
// baseline (2052.828 us; speedup 1.0000x reference)
//
#include <hip/hip_runtime.h>

#define BB 64
#define TT 512
#define EE 512
#define RR 2048
#define CPW 32    // columns per scan workgroup
#define RPG 16    // rows (batch) per group
#define NWGS 256  // 4 groups x 64 col-WGs
#define FPAD 16   // flag padding: 16 u32 = 64 B/flag
#define SLOT2 (BB * RR * 2)      // one S-history slot (f16, 256KB)
#define GRP2  (RPG * RR * 2)     // group slice within a slot (64KB)
#define SPIN_CAP (1 << 20)       // watchdog: fail fast instead of hanging

typedef _Float16 f16;
typedef f16 f16x8 __attribute__((ext_vector_type(8)));
typedef float f32x4 __attribute__((ext_vector_type(4)));

__device__ __forceinline__ float fast_tanh(float v) {
  float e = __expf(2.0f * v);
  return 1.0f - 2.0f / (e + 1.0f);
}

// write-through device-coherent 2B store (R2-R13 proven): lands at L3
__device__ __forceinline__ void storeS(f16* p, f16 h) {
  union { f16 h; unsigned short s; } u;
  u.h = h;
  __hip_atomic_store((unsigned short*)p, u.s, __ATOMIC_RELAXED, __HIP_MEMORY_SCOPE_AGENT);
}

__device__ __forceinline__ unsigned flag_ld(const unsigned* p) {
  return __hip_atomic_load(p, __ATOMIC_RELAXED, __HIP_MEMORY_SCOPE_AGENT);
}
__device__ __forceinline__ void flag_st(unsigned* p, unsigned v) {
  __hip_atomic_store(p, v, __ATOMIC_RELAXED, __HIP_MEMORY_SCOPE_AGENT);
}

// 8 plain cached 16B loads, imm offsets 0..448 (single-assignment makes caching safe)
__device__ __forceinline__ void issue8(f16x8* dst, unsigned voff, const f16* sbase) {
#pragma unroll
  for (int i = 0; i < 8; ++i)
    asm volatile("global_load_dwordx4 %0, %1, %2 offset:%c3"
                 : "=v"(dst[i]) : "v"(voff), "s"(sbase), "i"(64 * i) : "memory");
}
// 16 plain cached 16B loads (emb fragments), imm offsets 0..960
__device__ __forceinline__ void issue16(f16x8* dst, unsigned voff, const f16* sbase) {
#pragma unroll
  for (int i = 0; i < 16; ++i)
    asm volatile("global_load_dwordx4 %0, %1, %2 offset:%c3"
                 : "=v"(dst[i]) : "v"(voff), "s"(sbase), "i"(64 * i) : "memory");
}

template <int N>
__device__ __forceinline__ void wait_vm() {
  asm volatile("s_waitcnt vmcnt(%c0)" :: "i"(N) : "memory");
  __builtin_amdgcn_sched_barrier(0);   // rule #18
}

// ---------------- prep kernels ----------------

__global__ void prep_emb(const int* __restrict__ x, const float* __restrict__ ew,
                         f16* __restrict__ emb) {
  const int row = blockIdx.x;            // token index (b*T + t)
  const int tok = x[row];
  const float4* src = (const float4*)(ew + (size_t)tok * EE);
  f16* dst = emb + (size_t)row * EE;
  const int i = threadIdx.x;             // 128 threads, 4 f16 each
  float4 v = src[i];
  union { f16 h[4]; unsigned long long u; } p;
  p.h[0] = (f16)v.x; p.h[1] = (f16)v.y; p.h[2] = (f16)v.z; p.h[3] = (f16)v.w;
  ((unsigned long long*)dst)[i] = p.u;
}

__global__ void prep_winT(const float* __restrict__ Win, f16* __restrict__ WinT) {
  const int i = blockIdx.x * blockDim.x + threadIdx.x;  // over EE*RR
  if (i < EE * RR) {
    const int k = i / RR, n = i % RR;
    WinT[(size_t)n * EE + k] = (f16)Win[i];
  }
}

// ---------------- fused scan: reservoir recurrence + inline input projection ----------
// R13 core (single-assignment S-history, group-local, zero per-step fences,
// R6 flag protocol) + fused u-projection:
// * u_tau[16x32] per WG is computed IN the scan by waves 0/1 (one 16-col
//   n-tile each, K=512 = 16 MFMA chunks, WinT B-fragments pinned in VGPRs),
//   written to a parity-double-buffered 2KB LDS u-buffer, consumed at step
//   tau+1's reduce. Chunk accumulation order == proj_gemm's k0-loop =>
//   bit-identical u values => bit-identical output.
// * emb fragments are asm-loaded BEFORE the flag poll; the poll's implicit
//   vmcnt(0) (compiler waitcnt on flag_ld) plus explicit wait_vm<8> makes
//   them register-safe before the u-MFMAs (rule #18 guarded).
// * S_tau lives in its own fresh 256KB slot (slot tau-1), group-local slice:
//   cached A-loads are the launch's first cached touch of each address =>
//   always fresh from L3 (write-through stores). No U buffer, no bypass loads.

__launch_bounds__(512, 1)
__global__ void scan_kernel(const float* __restrict__ R, f16* __restrict__ Sh,
                            const f16* __restrict__ emb, const f16* __restrict__ WinT,
                            unsigned* __restrict__ flg) {
  __shared__ __align__(16) char ldsbuf[CPW * RR * 2 + 16 * 1040 + 2 * RPG * CPW * 4];
  f16* Rt = (f16*)ldsbuf;
  const char* RtB = (const char*)ldsbuf;
  float* ubuf = (float*)(ldsbuf + CPW * RR * 2 + 16 * 1040);  // [2][16][32] f32

  const int wg = blockIdx.x;
  const int xcd = wg & 7;                        // heuristic (perf only)
  const int grp = xcd >> 1;                      // group on XCD pair
  const int cw = ((wg >> 3) << 1) | (wg & 1);    // 0..63 within group
  const int nbase = cw * CPW;
  const int rbase = grp * RPG;
  const int tid = threadIdx.x;
  const int wv = tid >> 6, l = tid & 63;
  unsigned* gflags = flg + (size_t)grp * 64 * FPAD;
  unsigned* myflag = gflags + cw * FPAD;
  f16* Sg = Sh + (size_t)grp * (RPG * RR);       // group slice base (within slot 0)

  // prologue: one-time L1/L2 invalidate (cross-launch residue)
  __builtin_amdgcn_fence(__ATOMIC_ACQUIRE, "agent");

  const int r16 = l & 15, kb = l >> 4;
  const int mm = tid >> 5, cc = tid & 31;        // output element (row, col)

  // R column slice -> LDS (chunked conflict-free layout), once
  {
    const int c = tid & 31, kst = tid >> 5;
    for (int k = kst; k < RR; k += 16) {
      const float v = R[(size_t)k * RR + nbase + c];
      const int idx = ((k >> 5) << 10) + ((c >> 4) << 9) +
                      (((c & 15) << 2) + ((k >> 3) & 3)) * 8 + (k & 7);
      Rt[idx] = (f16)v;
    }
  }

  // WinT B-fragments for this WG's u-tile: waves 0/1, pinned in VGPRs
  f16x8 bfr[16];
  if (wv < 2) {
#pragma unroll
    for (int kc = 0; kc < 16; ++kc)
      bfr[kc] = *(const f16x8*)&WinT[(size_t)(nbase + wv * 16 + r16) * EE + kc * 32 + kb * 8];
  }
  __syncthreads();

  // prologue u_0 -> ubuf[0], u_1 -> ubuf[1]
  if (wv < 2) {
    f16x8 ebuf[16];
#pragma unroll
    for (int t01 = 0; t01 < 2; ++t01) {
      const unsigned ve = (unsigned)(((((rbase + r16) * TT) + t01) * EE + kb * 8) * 2);
      issue16(ebuf, ve, emb);
      wait_vm<0>();
      f32x4 au = {0.f, 0.f, 0.f, 0.f};
#pragma unroll
      for (int kc = 0; kc < 16; ++kc)
        au = __builtin_amdgcn_mfma_f32_16x16x32_f16(ebuf[kc], bfr[kc], au, 0, 0, 0);
#pragma unroll
      for (int j = 0; j < 4; ++j)
        ubuf[t01 * 512 + ((kb * 4 + j) * 32) + wv * 16 + r16] = au[j];
    }
  }
  __syncthreads();

  // tau = 1: S_1 = tanh(u_0) -> slot 0 (group slice); publish
  storeS(&Sg[(size_t)mm * RR + nbase + cc], (f16)fast_tanh(ubuf[mm * 32 + cc]));
  __syncthreads();                               // drains stores
  if (tid == 0) flag_st(myflag, 1u);

  const int kblk = (wv + cw) & 7;          // k-rotation: de-hotspot + octet polls
  const unsigned voffA = (unsigned)(((r16 * RR) + (kblk << 8) + kb * 8) * 2);
  const int bb0 = (r16 * 4 + kb) * 16;     // byte within 1024B chunk row
  // reduce-read coords for this thread's output element (mm, cc)
  const int ntr = cc >> 4;
  const int lred = (cc & 15) | ((mm >> 2) << 4);
  const int jred = mm & 3;

  f16x8 abuf[8];

  for (int tau = 2; tau <= TT; ++tau) {
    const unsigned need = (unsigned)(tau - 1);

    // emb fragments for u_tau issued BEFORE the poll (latency hides in spin)
    f16x8 ebuf[16];
    if (wv < 2) {
      const int te = (tau < TT) ? tau : TT - 1;  // tau==TT: harmless recompute
      const unsigned ve = (unsigned)(((((rbase + r16) * TT) + te) * EE + kb * 8) * 2);
      issue16(ebuf, ve, emb);
    }

    // per-wave poll of this wave's 8 producers (R6-proven shape);
    // flag_ld's compiler waitcnt also retires the emb loads
    {
      const unsigned* pp = &gflags[(size_t)(kblk * 8 + (l & 7)) * FPAD];
      unsigned fv = flag_ld(pp);
      int gd = 0;
      while (!__all(fv >= need) && ++gd < SPIN_CAP) {
        __builtin_amdgcn_s_sleep(1);
        fv = flag_ld(pp);
      }
    }

    const f16* sprev = Sh + (size_t)(tau - 2) * (BB * RR) + (size_t)grp * (RPG * RR);
    f16* snext = (f16*)((char*)Sh + (size_t)(tau - 1) * SLOT2) + (size_t)grp * (RPG * RR);

    // 8 cached state A-loads
    issue8(abuf, voffA, sprev);

    // u_tau MFMAs (waves 0/1) while state loads fly; ebuf guaranteed retired
    if (wv < 2) {
      wait_vm<8>();                          // 8 state loads out; emb retired
      f32x4 au = {0.f, 0.f, 0.f, 0.f};
#pragma unroll
      for (int kc = 0; kc < 16; ++kc)
        au = __builtin_amdgcn_mfma_f32_16x16x32_f16(ebuf[kc], bfr[kc], au, 0, 0, 0);
#pragma unroll
      for (int j = 0; j < 4; ++j)
        ubuf[(tau & 1) * 512 + ((kb * 4 + j) * 32) + wv * 16 + r16] = au[j];
    }

    f32x4 acc0 = {0.f, 0.f, 0.f, 0.f}, acc1 = {0.f, 0.f, 0.f, 0.f};
#define KSTEP(ks)                                                              \
  {                                                                            \
    const int kc = (kblk << 3) + (ks);                                         \
    f16x8 b0 = *(const f16x8*)(RtB + kc * 2048 + bb0);                         \
    f16x8 b1 = *(const f16x8*)(RtB + kc * 2048 + 1024 + bb0);                  \
    acc0 = __builtin_amdgcn_mfma_f32_16x16x32_f16(abuf[ks], b0, acc0, 0, 0, 0);\
    acc1 = __builtin_amdgcn_mfma_f32_16x16x32_f16(abuf[ks], b1, acc1, 0, 0, 0);\
  }
    wait_vm<4>();                            // A0..A3 ready
    KSTEP(0) KSTEP(1) KSTEP(2) KSTEP(3)
    wait_vm<0>();                            // A4..A7 ready
    KSTEP(4) KSTEP(5) KSTEP(6) KSTEP(7)
#undef KSTEP

    // partial accumulators -> LDS (padded per-wave copies), 8-way reduce
    {
      char* red = ldsbuf + CPW * RR * 2;
      *(f32x4*)(red + (wv * 2 + 0) * 1040 + l * 16) = acc0;
      *(f32x4*)(red + (wv * 2 + 1) * 1040 + l * 16) = acc1;
    }
    __syncthreads();
    {
      const char* red = ldsbuf + CPW * RR * 2;
      float s = 0.f;
#pragma unroll
      for (int w = 0; w < 8; ++w)
        s += *(const float*)(red + (w * 2 + ntr) * 1040 + lred * 16 + jred * 4);
      const float uval = ubuf[((tau - 1) & 1) * 512 + mm * 32 + cc];  // u_{tau-1}
      storeS(&snext[(size_t)mm * RR + nbase + cc], (f16)fast_tanh(s + uval));
    }
    __syncthreads();                         // drains stores (vmcnt0 at barrier)
    if (tid == 0) flag_st(myflag, (unsigned)tau);
  }
}

// ---------------- LayerNorm (group-local final-state layout) ----------------

__launch_bounds__(256, 1)
__global__ void ln_kernel(const char* __restrict__ slotbase, const float* __restrict__ gamma,
                          const float* __restrict__ beta, float* __restrict__ out) {
  const int b = blockIdx.x;
  const int tid = threadIdx.x;
  const f16* row = (const f16*)(slotbase + (size_t)(b >> 4) * GRP2) + (size_t)(b & 15) * RR;
  float vals[8];
  float lsum = 0.f, lsq = 0.f;
#pragma unroll
  for (int i = 0; i < 8; ++i) {
    float v = (float)row[tid + i * 256];
    vals[i] = v; lsum += v; lsq += v * v;
  }
#pragma unroll
  for (int off = 32; off >= 1; off >>= 1) {
    lsum += __shfl_xor(lsum, off);
    lsq  += __shfl_xor(lsq, off);
  }
  __shared__ float ps[4], pq[4];
  __shared__ float mu_s, rstd_s;
  const int wv = tid >> 6, l = tid & 63;
  if (l == 0) { ps[wv] = lsum; pq[wv] = lsq; }
  __syncthreads();
  if (tid == 0) {
    float s = 0.f, q = 0.f;
    for (int i = 0; i < 4; ++i) { s += ps[i]; q += pq[i]; }
    const float mu = s / RR;
    const float var = q / RR - mu * mu;
    mu_s = mu; rstd_s = rsqrtf(var + 1e-5f);
  }
  __syncthreads();
  const float mu = mu_s, rstd = rstd_s;
#pragma unroll
  for (int i = 0; i < 8; ++i) {
    const int idx = tid + i * 256;
    out[(size_t)b * RR + idx] = (vals[i] - mu) * rstd * gamma[idx] + beta[idx];
  }
}

// ---------------- launch ----------------

extern "C" void kernel_launch(void* const* d_in, const int* in_sizes, int n_in,
                              void* d_out, int out_size, void* d_ws, size_t ws_size,
                              hipStream_t stream) {
  const int*   x     = (const int*)d_in[0];
  const float* ew    = (const float*)d_in[1];
  const float* Rm    = (const float*)d_in[2];
  const float* Win   = (const float*)d_in[3];
  const float* gamma = (const float*)d_in[4];
  const float* beta  = (const float*)d_in[5];

  const size_t SH_OFF  = 0;                           // f16  512 slots x 256KB = 128MB
  const size_t EMB_OFF = (size_t)TT * SLOT2;          // f16  32768*512*2 = 32MB
  const size_t WT_OFF  = EMB_OFF + 33554432;          // f16  2048*512*2  = 2MB
  const size_t FLG_OFF = WT_OFF + 2097152;            // u32  256 flags x 64B
  const size_t NEED    = FLG_OFF + 16384;
  if (ws_size < NEED) {
    hipMemsetAsync(d_out, 0, (size_t)out_size * 4, stream);
    return;
  }
  char* ws = (char*)d_ws;
  f16*      Shist = (f16*)(ws + SH_OFF);
  f16*      emb   = (f16*)(ws + EMB_OFF);
  f16*      WinT  = (f16*)(ws + WT_OFF);
  unsigned* flg   = (unsigned*)(ws + FLG_OFF);

  hipMemsetAsync(flg, 0, 16384, stream);   // flags reset each launch (replay-safe)
  prep_emb<<<BB * TT, 128, 0, stream>>>(x, ew, emb);
  prep_winT<<<(EE * RR) / 256, 256, 0, stream>>>(Win, WinT);
  scan_kernel<<<NWGS, 512, 0, stream>>>(Rm, Shist, emb, WinT, flg);
  // S_512 lives in slot 511 (group-local slices)
  ln_kernel<<<BB, 256, 0, stream>>>(ws + (size_t)(TT - 1) * SLOT2,
                                    gamma, beta, (float*)d_out);
}

// Round 15
// 2047.418 us; speedup vs baseline: 1.0026x; 1.0026x over previous
//
#include <hip/hip_runtime.h>

#define BB 64
#define TT 512
#define EE 512
#define RR 2048
#define CPW 32    // columns per scan workgroup
#define RPG 16    // rows (batch) per group
#define NWGS 256  // 4 groups x 64 col-WGs
#define FPAD 16   // flag padding: 16 u32 = 64 B/flag
#define SLOT2 (BB * RR * 2)      // one S-history slot (f16, 256KB)
#define GRP2  (RPG * RR * 2)     // group slice within a slot (64KB)
#define SPIN_CAP (1 << 20)       // watchdog: fail fast instead of hanging

typedef _Float16 f16;
typedef f16 f16x8 __attribute__((ext_vector_type(8)));
typedef float f32x4 __attribute__((ext_vector_type(4)));

__device__ __forceinline__ float fast_tanh(float v) {
  float e = __expf(2.0f * v);
  return 1.0f - 2.0f / (e + 1.0f);
}

// write-through device-coherent 2B store (R2-R13 proven): lands at L3
__device__ __forceinline__ void storeS(f16* p, f16 h) {
  union { f16 h; unsigned short s; } u;
  u.h = h;
  __hip_atomic_store((unsigned short*)p, u.s, __ATOMIC_RELAXED, __HIP_MEMORY_SCOPE_AGENT);
}

__device__ __forceinline__ unsigned flag_ld(const unsigned* p) {
  return __hip_atomic_load(p, __ATOMIC_RELAXED, __HIP_MEMORY_SCOPE_AGENT);
}
__device__ __forceinline__ void flag_st(unsigned* p, unsigned v) {
  __hip_atomic_store(p, v, __ATOMIC_RELAXED, __HIP_MEMORY_SCOPE_AGENT);
}

// 8 plain cached 16B loads, imm offsets 0..448 (single-assignment makes caching safe)
__device__ __forceinline__ void issue8(f16x8* dst, unsigned voff, const f16* sbase) {
#pragma unroll
  for (int i = 0; i < 8; ++i)
    asm volatile("global_load_dwordx4 %0, %1, %2 offset:%c3"
                 : "=v"(dst[i]) : "v"(voff), "s"(sbase), "i"(64 * i) : "memory");
}
// 16 plain cached 16B loads (emb fragments), imm offsets 0..960
__device__ __forceinline__ void issue16(f16x8* dst, unsigned voff, const f16* sbase) {
#pragma unroll
  for (int i = 0; i < 16; ++i)
    asm volatile("global_load_dwordx4 %0, %1, %2 offset:%c3"
                 : "=v"(dst[i]) : "v"(voff), "s"(sbase), "i"(64 * i) : "memory");
}

template <int N>
__device__ __forceinline__ void wait_vm() {
  asm volatile("s_waitcnt vmcnt(%c0)" :: "i"(N) : "memory");
  __builtin_amdgcn_sched_barrier(0);   // rule #18
}

// ---------------- prep kernels ----------------

__global__ void prep_emb(const int* __restrict__ x, const float* __restrict__ ew,
                         f16* __restrict__ emb) {
  const int row = blockIdx.x;            // token index (b*T + t)
  const int tok = x[row];
  const float4* src = (const float4*)(ew + (size_t)tok * EE);
  f16* dst = emb + (size_t)row * EE;
  const int i = threadIdx.x;             // 128 threads, 4 f16 each
  float4 v = src[i];
  union { f16 h[4]; unsigned long long u; } p;
  p.h[0] = (f16)v.x; p.h[1] = (f16)v.y; p.h[2] = (f16)v.z; p.h[3] = (f16)v.w;
  ((unsigned long long*)dst)[i] = p.u;
}

__global__ void prep_winT(const float* __restrict__ Win, f16* __restrict__ WinT) {
  const int i = blockIdx.x * blockDim.x + threadIdx.x;  // over EE*RR
  if (i < EE * RR) {
    const int k = i / RR, n = i % RR;
    WinT[(size_t)n * EE + k] = (f16)Win[i];
  }
}

// ---------------- fused scan: reservoir recurrence + inline input projection ----------
// R13 core (single-assignment S-history, group-local, zero per-step fences,
// R6 flag protocol) + fused u-projection, R14-regression-fixed:
// * u_tau per WG (16x32, K=512, WinT B-frags pinned in VGPRs on waves 0/1)
//   is computed in the POST-PUBLISH slack window — after this WG's flag
//   publish, before its next poll. In steady state that window is the
//   straggler spread (~1.5-2us) > the u-block (~1.2us, emb-fetch bound), so
//   the work hides. R14's mistake: emb loads issued pre-poll were drained by
//   flag_ld's vmcnt(0), putting the fetch ON the critical path (+0.53us/step).
// * Chunk accumulation order == proj_gemm's k0-loop => bit-identical output.
// * S_tau lives in a fresh 256KB slot per step (group-local slice): cached
//   A-loads are the launch's first cached touch => always fresh from L3.
//   No U buffer, no proj_gemm kernel, no per-step fences.

__launch_bounds__(512, 1)
__global__ void scan_kernel(const float* __restrict__ R, f16* __restrict__ Sh,
                            const f16* __restrict__ emb, const f16* __restrict__ WinT,
                            unsigned* __restrict__ flg) {
  __shared__ __align__(16) char ldsbuf[CPW * RR * 2 + 16 * 1040 + 2 * RPG * CPW * 4];
  f16* Rt = (f16*)ldsbuf;
  const char* RtB = (const char*)ldsbuf;
  float* ubuf = (float*)(ldsbuf + CPW * RR * 2 + 16 * 1040);  // [2][16][32] f32

  const int wg = blockIdx.x;
  const int xcd = wg & 7;                        // heuristic (perf only)
  const int grp = xcd >> 1;                      // group on XCD pair
  const int cw = ((wg >> 3) << 1) | (wg & 1);    // 0..63 within group
  const int nbase = cw * CPW;
  const int rbase = grp * RPG;
  const int tid = threadIdx.x;
  const int wv = tid >> 6, l = tid & 63;
  unsigned* gflags = flg + (size_t)grp * 64 * FPAD;
  unsigned* myflag = gflags + cw * FPAD;
  f16* Sg = Sh + (size_t)grp * (RPG * RR);       // group slice base (within slot 0)

  // prologue: one-time L1/L2 invalidate (cross-launch residue)
  __builtin_amdgcn_fence(__ATOMIC_ACQUIRE, "agent");

  const int r16 = l & 15, kb = l >> 4;
  const int mm = tid >> 5, cc = tid & 31;        // output element (row, col)

  // R column slice -> LDS (chunked conflict-free layout), once
  {
    const int c = tid & 31, kst = tid >> 5;
    for (int k = kst; k < RR; k += 16) {
      const float v = R[(size_t)k * RR + nbase + c];
      const int idx = ((k >> 5) << 10) + ((c >> 4) << 9) +
                      (((c & 15) << 2) + ((k >> 3) & 3)) * 8 + (k & 7);
      Rt[idx] = (f16)v;
    }
  }

  // WinT B-fragments for this WG's u-tile: waves 0/1, pinned in VGPRs
  f16x8 bfr[16];
  if (wv < 2) {
#pragma unroll
    for (int kc = 0; kc < 16; ++kc)
      bfr[kc] = *(const f16x8*)&WinT[(size_t)(nbase + wv * 16 + r16) * EE + kc * 32 + kb * 8];
  }
  __syncthreads();

  // prologue u_0 -> ubuf[0], u_1 -> ubuf[1]
  if (wv < 2) {
    f16x8 ebuf[16];
#pragma unroll
    for (int t01 = 0; t01 < 2; ++t01) {
      const unsigned ve = (unsigned)(((((rbase + r16) * TT) + t01) * EE + kb * 8) * 2);
      issue16(ebuf, ve, emb);
      wait_vm<0>();
      f32x4 au = {0.f, 0.f, 0.f, 0.f};
#pragma unroll
      for (int kc = 0; kc < 16; ++kc)
        au = __builtin_amdgcn_mfma_f32_16x16x32_f16(ebuf[kc], bfr[kc], au, 0, 0, 0);
#pragma unroll
      for (int j = 0; j < 4; ++j)
        ubuf[t01 * 512 + ((kb * 4 + j) * 32) + wv * 16 + r16] = au[j];
    }
  }
  __syncthreads();

  // tau = 1: S_1 = tanh(u_0) -> slot 0 (group slice); publish
  storeS(&Sg[(size_t)mm * RR + nbase + cc], (f16)fast_tanh(ubuf[mm * 32 + cc]));
  __syncthreads();                               // drains stores
  if (tid == 0) flag_st(myflag, 1u);

  const int kblk = (wv + cw) & 7;          // k-rotation: de-hotspot + octet polls
  const unsigned voffA = (unsigned)(((r16 * RR) + (kblk << 8) + kb * 8) * 2);
  const int bb0 = (r16 * 4 + kb) * 16;     // byte within 1024B chunk row
  // reduce-read coords for this thread's output element (mm, cc)
  const int ntr = cc >> 4;
  const int lred = (cc & 15) | ((mm >> 2) << 4);
  const int jred = mm & 3;

  f16x8 abuf[8];

  for (int tau = 2; tau <= TT; ++tau) {
    const unsigned need = (unsigned)(tau - 1);

    // per-wave poll of this wave's 8 producers (R6-proven shape);
    // vmcnt queue is CLEAN here (u-block drained itself post-publish)
    {
      const unsigned* pp = &gflags[(size_t)(kblk * 8 + (l & 7)) * FPAD];
      unsigned fv = flag_ld(pp);
      int gd = 0;
      while (!__all(fv >= need) && ++gd < SPIN_CAP) {
        __builtin_amdgcn_s_sleep(1);
        fv = flag_ld(pp);
      }
    }

    const f16* sprev = Sh + (size_t)(tau - 2) * (BB * RR) + (size_t)grp * (RPG * RR);
    f16* snext = (f16*)((char*)Sh + (size_t)(tau - 1) * SLOT2) + (size_t)grp * (RPG * RR);

    // 8 cached state A-loads
    issue8(abuf, voffA, sprev);

    f32x4 acc0 = {0.f, 0.f, 0.f, 0.f}, acc1 = {0.f, 0.f, 0.f, 0.f};
#define KSTEP(ks)                                                              \
  {                                                                            \
    const int kc = (kblk << 3) + (ks);                                         \
    f16x8 b0 = *(const f16x8*)(RtB + kc * 2048 + bb0);                         \
    f16x8 b1 = *(const f16x8*)(RtB + kc * 2048 + 1024 + bb0);                  \
    acc0 = __builtin_amdgcn_mfma_f32_16x16x32_f16(abuf[ks], b0, acc0, 0, 0, 0);\
    acc1 = __builtin_amdgcn_mfma_f32_16x16x32_f16(abuf[ks], b1, acc1, 0, 0, 0);\
  }
    wait_vm<4>();                            // A0..A3 ready
    KSTEP(0) KSTEP(1) KSTEP(2) KSTEP(3)
    wait_vm<0>();                            // A4..A7 ready
    KSTEP(4) KSTEP(5) KSTEP(6) KSTEP(7)
#undef KSTEP

    // partial accumulators -> LDS (padded per-wave copies), 8-way reduce
    {
      char* red = ldsbuf + CPW * RR * 2;
      *(f32x4*)(red + (wv * 2 + 0) * 1040 + l * 16) = acc0;
      *(f32x4*)(red + (wv * 2 + 1) * 1040 + l * 16) = acc1;
    }
    __syncthreads();
    {
      const char* red = ldsbuf + CPW * RR * 2;
      float s = 0.f;
#pragma unroll
      for (int w = 0; w < 8; ++w)
        s += *(const float*)(red + (w * 2 + ntr) * 1040 + lred * 16 + jred * 4);
      const float uval = ubuf[((tau - 1) & 1) * 512 + mm * 32 + cc];  // u_{tau-1}
      storeS(&snext[(size_t)mm * RR + nbase + cc], (f16)fast_tanh(s + uval));
    }
    __syncthreads();                         // drains stores (vmcnt0 at barrier)
    if (tid == 0) flag_st(myflag, (unsigned)tau);

    // ---- u_tau for next step, in the post-publish slack (waves 0/1) ----
    // ubuf[tau&1] was last read at iter tau-1's reduce; safe to overwrite.
    // wait_vm<0> self-drains the emb loads so the next poll sees a clean
    // vmcnt queue (the R14 fix). Next reduce's read is barrier-ordered.
    if (wv < 2 && tau < TT) {
      f16x8 ebuf[16];
      const unsigned ve = (unsigned)(((((rbase + r16) * TT) + tau) * EE + kb * 8) * 2);
      issue16(ebuf, ve, emb);
      wait_vm<0>();
      f32x4 au = {0.f, 0.f, 0.f, 0.f};
#pragma unroll
      for (int kc = 0; kc < 16; ++kc)
        au = __builtin_amdgcn_mfma_f32_16x16x32_f16(ebuf[kc], bfr[kc], au, 0, 0, 0);
#pragma unroll
      for (int j = 0; j < 4; ++j)
        ubuf[(tau & 1) * 512 + ((kb * 4 + j) * 32) + wv * 16 + r16] = au[j];
    }
  }
}

// ---------------- LayerNorm (group-local final-state layout) ----------------

__launch_bounds__(256, 1)
__global__ void ln_kernel(const char* __restrict__ slotbase, const float* __restrict__ gamma,
                          const float* __restrict__ beta, float* __restrict__ out) {
  const int b = blockIdx.x;
  const int tid = threadIdx.x;
  const f16* row = (const f16*)(slotbase + (size_t)(b >> 4) * GRP2) + (size_t)(b & 15) * RR;
  float vals[8];
  float lsum = 0.f, lsq = 0.f;
#pragma unroll
  for (int i = 0; i < 8; ++i) {
    float v = (float)row[tid + i * 256];
    vals[i] = v; lsum += v; lsq += v * v;
  }
#pragma unroll
  for (int off = 32; off >= 1; off >>= 1) {
    lsum += __shfl_xor(lsum, off);
    lsq  += __shfl_xor(lsq, off);
  }
  __shared__ float ps[4], pq[4];
  __shared__ float mu_s, rstd_s;
  const int wv = tid >> 6, l = tid & 63;
  if (l == 0) { ps[wv] = lsum; pq[wv] = lsq; }
  __syncthreads();
  if (tid == 0) {
    float s = 0.f, q = 0.f;
    for (int i = 0; i < 4; ++i) { s += ps[i]; q += pq[i]; }
    const float mu = s / RR;
    const float var = q / RR - mu * mu;
    mu_s = mu; rstd_s = rsqrtf(var + 1e-5f);
  }
  __syncthreads();
  const float mu = mu_s, rstd = rstd_s;
#pragma unroll
  for (int i = 0; i < 8; ++i) {
    const int idx = tid + i * 256;
    out[(size_t)b * RR + idx] = (vals[i] - mu) * rstd * gamma[idx] + beta[idx];
  }
}

// ---------------- launch ----------------

extern "C" void kernel_launch(void* const* d_in, const int* in_sizes, int n_in,
                              void* d_out, int out_size, void* d_ws, size_t ws_size,
                              hipStream_t stream) {
  const int*   x     = (const int*)d_in[0];
  const float* ew    = (const float*)d_in[1];
  const float* Rm    = (const float*)d_in[2];
  const float* Win   = (const float*)d_in[3];
  const float* gamma = (const float*)d_in[4];
  const float* beta  = (const float*)d_in[5];

  const size_t SH_OFF  = 0;                           // f16  512 slots x 256KB = 128MB
  const size_t EMB_OFF = (size_t)TT * SLOT2;          // f16  32768*512*2 = 32MB
  const size_t WT_OFF  = EMB_OFF + 33554432;          // f16  2048*512*2  = 2MB
  const size_t FLG_OFF = WT_OFF + 2097152;            // u32  256 flags x 64B
  const size_t NEED    = FLG_OFF + 16384;
  if (ws_size < NEED) {
    hipMemsetAsync(d_out, 0, (size_t)out_size * 4, stream);
    return;
  }
  char* ws = (char*)d_ws;
  f16*      Shist = (f16*)(ws + SH_OFF);
  f16*      emb   = (f16*)(ws + EMB_OFF);
  f16*      WinT  = (f16*)(ws + WT_OFF);
  unsigned* flg   = (unsigned*)(ws + FLG_OFF);

  hipMemsetAsync(flg, 0, 16384, stream);   // flags reset each launch (replay-safe)
  prep_emb<<<BB * TT, 128, 0, stream>>>(x, ew, emb);
  prep_winT<<<(EE * RR) / 256, 256, 0, stream>>>(Win, WinT);
  scan_kernel<<<NWGS, 512, 0, stream>>>(Rm, Shist, emb, WinT, flg);
  // S_512 lives in slot 511 (group-local slices)
  ln_kernel<<<BB, 256, 0, stream>>>(ws + (size_t)(TT - 1) * SLOT2,
                                    gamma, beta, (float*)d_out);
}

// Round 16
// 1867.109 us; speedup vs baseline: 1.0995x; 1.0966x over previous
//
#include <hip/hip_runtime.h>

#define BB 64
#define TT 512
#define EE 512
#define RR 2048
#define CPW 32    // columns per scan workgroup
#define RPG 16    // rows (batch) per group
#define NWGS 256  // 4 groups x 64 col-WGs
#define FPAD 16   // flag padding: 16 u32 = 64 B/flag
#define SLOT2 (BB * RR * 2)      // one S-history slot (f16, 256KB)
#define GRP2  (RPG * RR * 2)     // group slice within a slot (64KB)
#define SPIN_CAP (1 << 20)       // watchdog: fail fast instead of hanging

typedef _Float16 f16;
typedef f16 f16x8 __attribute__((ext_vector_type(8)));
typedef float f32x4 __attribute__((ext_vector_type(4)));

__device__ __forceinline__ float fast_tanh(float v) {
  float e = __expf(2.0f * v);
  return 1.0f - 2.0f / (e + 1.0f);
}

// write-through device-coherent 2B store (R2-R15 proven): lands at L3
__device__ __forceinline__ void storeS(f16* p, f16 h) {
  union { f16 h; unsigned short s; } u;
  u.h = h;
  __hip_atomic_store((unsigned short*)p, u.s, __ATOMIC_RELAXED, __HIP_MEMORY_SCOPE_AGENT);
}

__device__ __forceinline__ unsigned flag_ld(const unsigned* p) {
  return __hip_atomic_load(p, __ATOMIC_RELAXED, __HIP_MEMORY_SCOPE_AGENT);
}
__device__ __forceinline__ void flag_st(unsigned* p, unsigned v) {
  __hip_atomic_store(p, v, __ATOMIC_RELAXED, __HIP_MEMORY_SCOPE_AGENT);
}

// 8 plain cached 16B loads, imm offsets 0..448 (single-assignment makes caching safe)
__device__ __forceinline__ void issue8(f16x8* dst, unsigned voff, const f16* sbase) {
#pragma unroll
  for (int i = 0; i < 8; ++i)
    asm volatile("global_load_dwordx4 %0, %1, %2 offset:%c3"
                 : "=v"(dst[i]) : "v"(voff), "s"(sbase), "i"(64 * i) : "memory");
}
// 2 plain cached 16B loads (this wave's emb u-chunks), imm 0 / 64
__device__ __forceinline__ void issue2(f16x8* dst, unsigned voff, const f16* sbase) {
  asm volatile("global_load_dwordx4 %0, %1, %2"
               : "=v"(dst[0]) : "v"(voff), "s"(sbase) : "memory");
  asm volatile("global_load_dwordx4 %0, %1, %2 offset:64"
               : "=v"(dst[1]) : "v"(voff), "s"(sbase) : "memory");
}

template <int N>
__device__ __forceinline__ void wait_vm() {
  asm volatile("s_waitcnt vmcnt(%c0)" :: "i"(N) : "memory");
  __builtin_amdgcn_sched_barrier(0);   // rule #18
}

// ---------------- prep kernels ----------------

__global__ void prep_emb(const int* __restrict__ x, const float* __restrict__ ew,
                         f16* __restrict__ emb) {
  const int row = blockIdx.x;            // token index (b*T + t)
  const int tok = x[row];
  const float4* src = (const float4*)(ew + (size_t)tok * EE);
  f16* dst = emb + (size_t)row * EE;
  const int i = threadIdx.x;             // 128 threads, 4 f16 each
  float4 v = src[i];
  union { f16 h[4]; unsigned long long u; } p;
  p.h[0] = (f16)v.x; p.h[1] = (f16)v.y; p.h[2] = (f16)v.z; p.h[3] = (f16)v.w;
  ((unsigned long long*)dst)[i] = p.u;
}

__global__ void prep_winT(const float* __restrict__ Win, f16* __restrict__ WinT) {
  const int i = blockIdx.x * blockDim.x + threadIdx.x;  // over EE*RR
  if (i < EE * RR) {
    const int k = i / RR, n = i % RR;
    WinT[(size_t)n * EE + k] = (f16)Win[i];
  }
}

// ---------------- fused scan: recurrence + distributed inline projection ----------
// R13 core (single-assignment S-history slots, group-local, zero per-step
// fences, R6 flag protocol) + u-projection DISTRIBUTED across all 8 waves:
// * u's K=512 split into 16 chunks of 32; wave wv owns chunks {2wv, 2wv+1}.
//   Per step it appends 2 emb loads to the A-load queue and folds 4 MFMAs
//   (chunk x col-half, WinT frags pinned in 16 VGPRs) into acc0/acc1. The
//   u-sum rides the EXISTING 8-way LDS reduce — no separate u-phase, no
//   wave asymmetry (R14/R15's regression), ~0.05us/step added serial cost.
// * Step tau=1 uses the same machinery: acc = u_0 partials only -> reduce ->
//   S_1 = tanh(sum).
// * S_tau lives in a fresh 256KB slot per step (group-local slice): cached
//   A-loads are the launch's first cached touch => always fresh from L3.
//   No U buffer, no proj_gemm kernel, no per-step fences.

__launch_bounds__(512, 1)
__global__ void scan_kernel(const float* __restrict__ R, f16* __restrict__ Sh,
                            const f16* __restrict__ emb, const f16* __restrict__ WinT,
                            unsigned* __restrict__ flg) {
  __shared__ __align__(16) char ldsbuf[CPW * RR * 2 + 16 * 1040];  // 128K Rt + reduce buf
  f16* Rt = (f16*)ldsbuf;
  const char* RtB = (const char*)ldsbuf;

  const int wg = blockIdx.x;
  const int xcd = wg & 7;                        // heuristic (perf only)
  const int grp = xcd >> 1;                      // group on XCD pair
  const int cw = ((wg >> 3) << 1) | (wg & 1);    // 0..63 within group
  const int nbase = cw * CPW;
  const int rbase = grp * RPG;
  const int tid = threadIdx.x;
  const int wv = tid >> 6, l = tid & 63;
  unsigned* gflags = flg + (size_t)grp * 64 * FPAD;
  unsigned* myflag = gflags + cw * FPAD;
  f16* Sg = Sh + (size_t)grp * (RPG * RR);       // group slice base (within slot 0)

  // prologue: one-time L1/L2 invalidate (cross-launch residue)
  __builtin_amdgcn_fence(__ATOMIC_ACQUIRE, "agent");

  const int r16 = l & 15, kb = l >> 4;
  const int mm = tid >> 5, cc = tid & 31;        // output element (row, col)
  // reduce-read coords for (mm, cc)
  const int ntr = cc >> 4;
  const int lred = (cc & 15) | ((mm >> 2) << 4);
  const int jred = mm & 3;
  char* red = ldsbuf + CPW * RR * 2;

  // R column slice -> LDS (chunked conflict-free layout), once
  {
    const int c = tid & 31, kst = tid >> 5;
    for (int k = kst; k < RR; k += 16) {
      const float v = R[(size_t)k * RR + nbase + c];
      const int idx = ((k >> 5) << 10) + ((c >> 4) << 9) +
                      (((c & 15) << 2) + ((k >> 3) & 3)) * 8 + (k & 7);
      Rt[idx] = (f16)v;
    }
  }

  // WinT fragments for this wave's 2 u-chunks x 2 col-halves (16 VGPRs)
  f16x8 wfr[2][2];
#pragma unroll
  for (int c2 = 0; c2 < 2; ++c2)
#pragma unroll
    for (int nt = 0; nt < 2; ++nt)
      wfr[c2][nt] = *(const f16x8*)&WinT[(size_t)(nbase + nt * 16 + r16) * EE +
                                         (2 * wv + c2) * 32 + kb * 8];

  // emb byte offset for this wave's chunks at t: voffE0 + t*EE*2
  const unsigned voffE0 =
      (unsigned)((((size_t)(rbase + r16) * TT) * EE + 2 * wv * 32 + kb * 8) * 2);

  // ---- tau = 1: S_1 = tanh(u_0) via the same distributed-reduce machinery ----
  {
    f16x8 ebuf[2];
    issue2(ebuf, voffE0 /* t=0 */, emb);
    wait_vm<0>();
    f32x4 a0 = {0.f, 0.f, 0.f, 0.f}, a1 = {0.f, 0.f, 0.f, 0.f};
#pragma unroll
    for (int c2 = 0; c2 < 2; ++c2) {
      a0 = __builtin_amdgcn_mfma_f32_16x16x32_f16(ebuf[c2], wfr[c2][0], a0, 0, 0, 0);
      a1 = __builtin_amdgcn_mfma_f32_16x16x32_f16(ebuf[c2], wfr[c2][1], a1, 0, 0, 0);
    }
    *(f32x4*)(red + (wv * 2 + 0) * 1040 + l * 16) = a0;
    *(f32x4*)(red + (wv * 2 + 1) * 1040 + l * 16) = a1;
    __syncthreads();                       // also covers the Rt writes above
    float s = 0.f;
#pragma unroll
    for (int w = 0; w < 8; ++w)
      s += *(const float*)(red + (w * 2 + ntr) * 1040 + lred * 16 + jred * 4);
    storeS(&Sg[(size_t)mm * RR + nbase + cc], (f16)fast_tanh(s));
    __syncthreads();                       // drains stores + red reads done
    if (tid == 0) flag_st(myflag, 1u);
  }

  const int kblk = (wv + cw) & 7;          // k-rotation: de-hotspot + octet polls
  const unsigned voffA = (unsigned)(((r16 * RR) + (kblk << 8) + kb * 8) * 2);
  const int bb0 = (r16 * 4 + kb) * 16;     // byte within 1024B chunk row

  f16x8 abuf[8];

  for (int tau = 2; tau <= TT; ++tau) {
    const unsigned need = (unsigned)(tau - 1);

    // per-wave poll of this wave's 8 producers (R6-proven shape); clean queue
    {
      const unsigned* pp = &gflags[(size_t)(kblk * 8 + (l & 7)) * FPAD];
      unsigned fv = flag_ld(pp);
      int gd = 0;
      while (!__all(fv >= need) && ++gd < SPIN_CAP) {
        __builtin_amdgcn_s_sleep(1);
        fv = flag_ld(pp);
      }
    }

    const f16* sprev = Sh + (size_t)(tau - 2) * (BB * RR) + (size_t)grp * (RPG * RR);
    f16* snext = (f16*)((char*)Sh + (size_t)(tau - 1) * SLOT2) + (size_t)grp * (RPG * RR);

    // queue: A0..A7 (state), E0,E1 (emb chunks for u_{tau-1})
    issue8(abuf, voffA, sprev);
    f16x8 ebuf[2];
    issue2(ebuf, voffE0 + (unsigned)((tau - 1) * (EE * 2)), emb);

    f32x4 acc0 = {0.f, 0.f, 0.f, 0.f}, acc1 = {0.f, 0.f, 0.f, 0.f};
#define KSTEP(ks)                                                              \
  {                                                                            \
    const int kc = (kblk << 3) + (ks);                                         \
    f16x8 b0 = *(const f16x8*)(RtB + kc * 2048 + bb0);                         \
    f16x8 b1 = *(const f16x8*)(RtB + kc * 2048 + 1024 + bb0);                  \
    acc0 = __builtin_amdgcn_mfma_f32_16x16x32_f16(abuf[ks], b0, acc0, 0, 0, 0);\
    acc1 = __builtin_amdgcn_mfma_f32_16x16x32_f16(abuf[ks], b1, acc1, 0, 0, 0);\
  }
    wait_vm<6>();                            // A0..A3 ready (A4..7,E out)
    KSTEP(0) KSTEP(1) KSTEP(2) KSTEP(3)
    wait_vm<2>();                            // A4..A7 ready (E out)
    KSTEP(4) KSTEP(5) KSTEP(6) KSTEP(7)
#undef KSTEP
    wait_vm<0>();                            // E0,E1 ready
#pragma unroll
    for (int c2 = 0; c2 < 2; ++c2) {         // fold u-partials into acc
      acc0 = __builtin_amdgcn_mfma_f32_16x16x32_f16(ebuf[c2], wfr[c2][0], acc0, 0, 0, 0);
      acc1 = __builtin_amdgcn_mfma_f32_16x16x32_f16(ebuf[c2], wfr[c2][1], acc1, 0, 0, 0);
    }

    // partial accumulators -> LDS (padded per-wave copies), 8-way reduce
    *(f32x4*)(red + (wv * 2 + 0) * 1040 + l * 16) = acc0;
    *(f32x4*)(red + (wv * 2 + 1) * 1040 + l * 16) = acc1;
    __syncthreads();
    {
      float s = 0.f;
#pragma unroll
      for (int w = 0; w < 8; ++w)
        s += *(const float*)(red + (w * 2 + ntr) * 1040 + lred * 16 + jred * 4);
      storeS(&snext[(size_t)mm * RR + nbase + cc], (f16)fast_tanh(s));
    }
    __syncthreads();                         // drains stores (vmcnt0 at barrier)
    if (tid == 0) flag_st(myflag, (unsigned)tau);
  }
}

// ---------------- LayerNorm (group-local final-state layout) ----------------

__launch_bounds__(256, 1)
__global__ void ln_kernel(const char* __restrict__ slotbase, const float* __restrict__ gamma,
                          const float* __restrict__ beta, float* __restrict__ out) {
  const int b = blockIdx.x;
  const int tid = threadIdx.x;
  const f16* row = (const f16*)(slotbase + (size_t)(b >> 4) * GRP2) + (size_t)(b & 15) * RR;
  float vals[8];
  float lsum = 0.f, lsq = 0.f;
#pragma unroll
  for (int i = 0; i < 8; ++i) {
    float v = (float)row[tid + i * 256];
    vals[i] = v; lsum += v; lsq += v * v;
  }
#pragma unroll
  for (int off = 32; off >= 1; off >>= 1) {
    lsum += __shfl_xor(lsum, off);
    lsq  += __shfl_xor(lsq, off);
  }
  __shared__ float ps[4], pq[4];
  __shared__ float mu_s, rstd_s;
  const int wv = tid >> 6, l = tid & 63;
  if (l == 0) { ps[wv] = lsum; pq[wv] = lsq; }
  __syncthreads();
  if (tid == 0) {
    float s = 0.f, q = 0.f;
    for (int i = 0; i < 4; ++i) { s += ps[i]; q += pq[i]; }
    const float mu = s / RR;
    const float var = q / RR - mu * mu;
    mu_s = mu; rstd_s = rsqrtf(var + 1e-5f);
  }
  __syncthreads();
  const float mu = mu_s, rstd = rstd_s;
#pragma unroll
  for (int i = 0; i < 8; ++i) {
    const int idx = tid + i * 256;
    out[(size_t)b * RR + idx] = (vals[i] - mu) * rstd * gamma[idx] + beta[idx];
  }
}

// ---------------- launch ----------------

extern "C" void kernel_launch(void* const* d_in, const int* in_sizes, int n_in,
                              void* d_out, int out_size, void* d_ws, size_t ws_size,
                              hipStream_t stream) {
  const int*   x     = (const int*)d_in[0];
  const float* ew    = (const float*)d_in[1];
  const float* Rm    = (const float*)d_in[2];
  const float* Win   = (const float*)d_in[3];
  const float* gamma = (const float*)d_in[4];
  const float* beta  = (const float*)d_in[5];

  const size_t SH_OFF  = 0;                           // f16  512 slots x 256KB = 128MB
  const size_t EMB_OFF = (size_t)TT * SLOT2;          // f16  32768*512*2 = 32MB
  const size_t WT_OFF  = EMB_OFF + 33554432;          // f16  2048*512*2  = 2MB
  const size_t FLG_OFF = WT_OFF + 2097152;            // u32  256 flags x 64B
  const size_t NEED    = FLG_OFF + 16384;
  if (ws_size < NEED) {
    hipMemsetAsync(d_out, 0, (size_t)out_size * 4, stream);
    return;
  }
  char* ws = (char*)d_ws;
  f16*      Shist = (f16*)(ws + SH_OFF);
  f16*      emb   = (f16*)(ws + EMB_OFF);
  f16*      WinT  = (f16*)(ws + WT_OFF);
  unsigned* flg   = (unsigned*)(ws + FLG_OFF);

  hipMemsetAsync(flg, 0, 16384, stream);   // flags reset each launch (replay-safe)
  prep_emb<<<BB * TT, 128, 0, stream>>>(x, ew, emb);
  prep_winT<<<(EE * RR) / 256, 256, 0, stream>>>(Win, WinT);
  scan_kernel<<<NWGS, 512, 0, stream>>>(Rm, Shist, emb, WinT, flg);
  // S_512 lives in slot 511 (group-local slices)
  ln_kernel<<<BB, 256, 0, stream>>>(ws + (size_t)(TT - 1) * SLOT2,
                                    gamma, beta, (float*)d_out);
}